// Round 3
// baseline (42.597 us; speedup 1.0000x reference)
//
#include <hip/hip_runtime.h>

// RoPE transform: out[b,s,f] = Q_f @ R[b,s,f] @ Q_f^T
// Q_f = (I - S_f)(I + S_f)^{-1} = 2*(I + S_f)^{-1} - I   (Cayley, orthogonal)
//
// DIAGNOSTIC ROUND: main kernel launched 3x (idempotent, identical output) to
// measure per-replay fixed overhead vs per-kernel time:
//   dur(n) = o + n*k;  R2 measured o + k = 21.2 us.
//   dur3 ~= 43 us  -> k ~= 11 (BW-bound kernel) + o ~= 10 (fixed overhead)
//   dur3 ~= 63 us  -> k ~= 21 (kernel itself slow; optimize write path next)

#define NFREQ 16
#define NROWS (4 * 8192 * 16 * 4)   // 2,097,152 rows
#define THREADS 256
#define QPAD 20                      // row stride in floats: 80B, 16B-aligned

__global__ void compute_Q_kernel(const float* __restrict__ skew,
                                 float* __restrict__ Qg)
{
    const int t = threadIdx.x;
    if (t >= NFREQ) return;
    // M = I + S. triu order: (0,1)(0,2)(0,3)(1,2)(1,3)(2,3)
    const double p0 = skew[t * 6 + 0];
    const double p1 = skew[t * 6 + 1];
    const double p2 = skew[t * 6 + 2];
    const double p3 = skew[t * 6 + 3];
    const double p4 = skew[t * 6 + 4];
    const double p5 = skew[t * 6 + 5];
    double M[4][4] = {
        { 1.0,  p0,  p1,  p2},
        {-p0,  1.0,  p3,  p4},
        {-p1,  -p3, 1.0,  p5},
        {-p2,  -p4, -p5, 1.0}};
    double Inv[4][4] = {{1,0,0,0},{0,1,0,0},{0,0,1,0},{0,0,0,1}};
    // Gauss-Jordan, no pivoting (symmetric part of M is I -> SPD-stable).
    #pragma unroll
    for (int c = 0; c < 4; ++c) {
        const double piv = 1.0 / M[c][c];
        #pragma unroll
        for (int j = 0; j < 4; ++j) { M[c][j] *= piv; Inv[c][j] *= piv; }
        #pragma unroll
        for (int r = 0; r < 4; ++r) {
            if (r == c) continue;
            const double fac = M[r][c];
            #pragma unroll
            for (int j = 0; j < 4; ++j) {
                M[r][j]   -= fac * M[c][j];
                Inv[r][j] -= fac * Inv[c][j];
            }
        }
    }
    #pragma unroll
    for (int i = 0; i < 4; ++i)
        #pragma unroll
        for (int j = 0; j < 4; ++j)
            Qg[t * 16 + i * 4 + j] =
                (float)(2.0 * Inv[i][j] - (i == j ? 1.0 : 0.0));
}

// Broadcast lane (quadbase + J)'s value to all 4 lanes of the quad. Free VALU.
template <int J>
__device__ __forceinline__ float4 quad_bcast(float4 v)
{
    constexpr int ctrl = J * 0x55;   // J | J<<2 | J<<4 | J<<6
    float4 o;
    o.x = __int_as_float(__builtin_amdgcn_mov_dpp(__float_as_int(v.x), ctrl, 0xF, 0xF, true));
    o.y = __int_as_float(__builtin_amdgcn_mov_dpp(__float_as_int(v.y), ctrl, 0xF, 0xF, true));
    o.z = __int_as_float(__builtin_amdgcn_mov_dpp(__float_as_int(v.z), ctrl, 0xF, 0xF, true));
    o.w = __int_as_float(__builtin_amdgcn_mov_dpp(__float_as_int(v.w), ctrl, 0xF, 0xF, true));
    return o;
}

__device__ __forceinline__ float dot4(float4 a, float4 b)
{
    return a.x * b.x + a.y * b.y + a.z * b.z + a.w * b.w;
}

__global__ __launch_bounds__(THREADS)
void rope_rows_kernel(const float* __restrict__ Qg,
                      const float* __restrict__ Rin,
                      float* __restrict__ out)
{
    __shared__ float Qs[NFREQ * QPAD];

    const int t = threadIdx.x;
    // Coalesced 1KB Q load: thread t -> freq t>>4, elem t&15.
    Qs[(t >> 4) * QPAD + (t & 15)] = Qg[t];
    __syncthreads();

    const int g = blockIdx.x * THREADS + t;   // global row id
    const int i = g & 3;                      // row within 4x4 block
    const int f = (g >> 2) & (NFREQ - 1);     // frequency

    // Perfectly coalesced: lane-contiguous 16B.
    const float4 r = reinterpret_cast<const float4*>(Rin)[g];

    const float4* Qrow = reinterpret_cast<const float4*>(&Qs[f * QPAD]);
    const float4 q0 = Qrow[0], q1 = Qrow[1], q2 = Qrow[2], q3 = Qrow[3];
    const float4 qi = Qrow[i];                // own row of Q

    // T row i = sum_j Q[i][j] * (R row j); R rows live in the quad's lanes.
    float4 T;
    {
        const float4 r0 = quad_bcast<0>(r);
        T.x = qi.x * r0.x; T.y = qi.x * r0.y; T.z = qi.x * r0.z; T.w = qi.x * r0.w;
        const float4 r1 = quad_bcast<1>(r);
        T.x += qi.y * r1.x; T.y += qi.y * r1.y; T.z += qi.y * r1.z; T.w += qi.y * r1.w;
        const float4 r2 = quad_bcast<2>(r);
        T.x += qi.z * r2.x; T.y += qi.z * r2.y; T.z += qi.z * r2.z; T.w += qi.z * r2.w;
        const float4 r3 = quad_bcast<3>(r);
        T.x += qi.w * r3.x; T.y += qi.w * r3.y; T.z += qi.w * r3.z; T.w += qi.w * r3.w;
    }

    // O row i = T . Q^T rows  ->  O[i][k] = dot(T, Q row k)
    float4 o;
    o.x = dot4(T, q0);
    o.y = dot4(T, q1);
    o.z = dot4(T, q2);
    o.w = dot4(T, q3);

    reinterpret_cast<float4*>(out)[g] = o;    // coalesced 16B/lane
}

extern "C" void kernel_launch(void* const* d_in, const int* in_sizes, int n_in,
                              void* d_out, int out_size, void* d_ws, size_t ws_size,
                              hipStream_t stream)
{
    const float* skew = (const float*)d_in[0];   // [16, 6]
    const float* Rin  = (const float*)d_in[1];   // [4, 8192, 16, 4, 4]
    float* out        = (float*)d_out;
    float* Qg         = (float*)d_ws;            // [16][16] floats = 1KB

    compute_Q_kernel<<<1, 64, 0, stream>>>(skew, Qg);
    // 3x identical launches: slope gives per-kernel time, intercept = overhead.
    rope_rows_kernel<<<NROWS / THREADS, THREADS, 0, stream>>>(Qg, Rin, out);
    rope_rows_kernel<<<NROWS / THREADS, THREADS, 0, stream>>>(Qg, Rin, out);
    rope_rows_kernel<<<NROWS / THREADS, THREADS, 0, stream>>>(Qg, Rin, out);
}

// Round 5
// 20.749 us; speedup vs baseline: 2.0529x; 2.0529x over previous
//
#include <hip/hip_runtime.h>

// RoPE transform: out[b,s,f] = Q_f @ R[b,s,f] @ Q_f^T
// Q_f = (I - S_f)(I + S_f)^{-1} = 2*(I + S_f)^{-1} - I   (Cayley, orthogonal)
//
// Shapes: skew_params [16, 6] f32, rope_matrices [4, 8192, 16, 4, 4] f32.
//
// Measured (R3 slope test): main kernel alone = 10.7 us = 6.26 TB/s for the
// 67 MB stream -> at the achievable HBM ceiling. Reported dur_us carries
// ~10.5 us fixed per-replay overhead on top.
//
// Two kernels:
//  1. compute_Q_kernel: 16 lanes invert (I+S)_f in f64, write Q [16][16] to ws.
//  2. rope_rows_kernel: one lane per 4x4-matrix ROW (2M rows). Lane-contiguous
//     nontemporal float4 load/store; rows exchanged within each aligned 4-lane
//     quad via DPP quad_perm broadcasts; Q read from LDS.

#define NFREQ 16
#define NROWS (4 * 8192 * 16 * 4)   // 2,097,152 rows
#define THREADS 256
#define QPAD 20                      // row stride in floats: 80B, 16B-aligned

typedef float vf4 __attribute__((ext_vector_type(4)));  // native clang vector
                                                        // (nontemporal-legal)

__global__ void compute_Q_kernel(const float* __restrict__ skew,
                                 float* __restrict__ Qg)
{
    const int t = threadIdx.x;
    if (t >= NFREQ) return;
    // M = I + S. triu order: (0,1)(0,2)(0,3)(1,2)(1,3)(2,3)
    const double p0 = skew[t * 6 + 0];
    const double p1 = skew[t * 6 + 1];
    const double p2 = skew[t * 6 + 2];
    const double p3 = skew[t * 6 + 3];
    const double p4 = skew[t * 6 + 4];
    const double p5 = skew[t * 6 + 5];
    double M[4][4] = {
        { 1.0,  p0,  p1,  p2},
        {-p0,  1.0,  p3,  p4},
        {-p1,  -p3, 1.0,  p5},
        {-p2,  -p4, -p5, 1.0}};
    double Inv[4][4] = {{1,0,0,0},{0,1,0,0},{0,0,1,0},{0,0,0,1}};
    // Gauss-Jordan, no pivoting (symmetric part of M is I -> SPD-stable).
    #pragma unroll
    for (int c = 0; c < 4; ++c) {
        const double piv = 1.0 / M[c][c];
        #pragma unroll
        for (int j = 0; j < 4; ++j) { M[c][j] *= piv; Inv[c][j] *= piv; }
        #pragma unroll
        for (int r = 0; r < 4; ++r) {
            if (r == c) continue;
            const double fac = M[r][c];
            #pragma unroll
            for (int j = 0; j < 4; ++j) {
                M[r][j]   -= fac * M[c][j];
                Inv[r][j] -= fac * Inv[c][j];
            }
        }
    }
    #pragma unroll
    for (int i = 0; i < 4; ++i)
        #pragma unroll
        for (int j = 0; j < 4; ++j)
            Qg[t * 16 + i * 4 + j] =
                (float)(2.0 * Inv[i][j] - (i == j ? 1.0 : 0.0));
}

// Broadcast lane (quadbase + J)'s value to all 4 lanes of the quad. Free VALU.
template <int J>
__device__ __forceinline__ vf4 quad_bcast(vf4 v)
{
    constexpr int ctrl = J * 0x55;   // J | J<<2 | J<<4 | J<<6
    vf4 o;
    o.x = __int_as_float(__builtin_amdgcn_mov_dpp(__float_as_int(v.x), ctrl, 0xF, 0xF, true));
    o.y = __int_as_float(__builtin_amdgcn_mov_dpp(__float_as_int(v.y), ctrl, 0xF, 0xF, true));
    o.z = __int_as_float(__builtin_amdgcn_mov_dpp(__float_as_int(v.z), ctrl, 0xF, 0xF, true));
    o.w = __int_as_float(__builtin_amdgcn_mov_dpp(__float_as_int(v.w), ctrl, 0xF, 0xF, true));
    return o;
}

__device__ __forceinline__ float dot4(vf4 a, vf4 b)
{
    return a.x * b.x + a.y * b.y + a.z * b.z + a.w * b.w;
}

__global__ __launch_bounds__(THREADS)
void rope_rows_kernel(const float* __restrict__ Qg,
                      const float* __restrict__ Rin,
                      float* __restrict__ out)
{
    __shared__ float Qs[NFREQ * QPAD];

    const int t = threadIdx.x;
    // Coalesced 1KB Q load: thread t -> freq t>>4, elem t&15.
    Qs[(t >> 4) * QPAD + (t & 15)] = Qg[t];
    __syncthreads();

    const int g = blockIdx.x * THREADS + t;   // global row id
    const int i = g & 3;                      // row within 4x4 block
    const int f = (g >> 2) & (NFREQ - 1);     // frequency

    // Perfectly coalesced, nontemporal (read-once stream): 16B/lane.
    const vf4 r =
        __builtin_nontemporal_load(reinterpret_cast<const vf4*>(Rin) + g);

    const vf4* Qrow = reinterpret_cast<const vf4*>(&Qs[f * QPAD]);
    const vf4 q0 = Qrow[0], q1 = Qrow[1], q2 = Qrow[2], q3 = Qrow[3];
    const vf4 qi = Qrow[i];                  // own row of Q

    // T row i = sum_j Q[i][j] * (R row j); R rows live in the quad's lanes.
    vf4 T;
    {
        const vf4 r0 = quad_bcast<0>(r);
        T = qi.x * r0;
        const vf4 r1 = quad_bcast<1>(r);
        T += qi.y * r1;
        const vf4 r2 = quad_bcast<2>(r);
        T += qi.z * r2;
        const vf4 r3 = quad_bcast<3>(r);
        T += qi.w * r3;
    }

    // O row i = T . Q^T rows  ->  O[i][k] = dot(T, Q row k)
    vf4 o;
    o.x = dot4(T, q0);
    o.y = dot4(T, q1);
    o.z = dot4(T, q2);
    o.w = dot4(T, q3);

    // Write-once stream: nontemporal 16B/lane.
    __builtin_nontemporal_store(o, reinterpret_cast<vf4*>(out) + g);
}

extern "C" void kernel_launch(void* const* d_in, const int* in_sizes, int n_in,
                              void* d_out, int out_size, void* d_ws, size_t ws_size,
                              hipStream_t stream)
{
    const float* skew = (const float*)d_in[0];   // [16, 6]
    const float* Rin  = (const float*)d_in[1];   // [4, 8192, 16, 4, 4]
    float* out        = (float*)d_out;
    float* Qg         = (float*)d_ws;            // [16][16] floats = 1KB

    compute_Q_kernel<<<1, 64, 0, stream>>>(skew, Qg);
    rope_rows_kernel<<<NROWS / THREADS, THREADS, 0, stream>>>(Qg, Rin, out);
}